// Round 1
// baseline (322.063 us; speedup 1.0000x reference)
//
#include <hip/hip_runtime.h>

constexpr int Dd = 128, Hh = 128, Ww = 128;
constexpr int NVOX = Dd * Hh * Ww;      // 2^21 per batch
constexpr int NB = 2;
constexpr int NC = 4;
constexpr int TOTAL = NB * NVOX;        // 4,194,304

// Kernel 1: per-voxel argmax (first-wins, matches jnp.argmax) + cross entropy
__global__ __launch_bounds__(256) void argmax_ce_kernel(
    const float* __restrict__ x, const int* __restrict__ y,
    unsigned char* __restrict__ P, float* __restrict__ ce)
{
    int i = blockIdx.x * 256 + threadIdx.x;
    if (i >= TOTAL) return;
    int b = i >> 21;            // NVOX = 2^21
    int v = i & (NVOX - 1);
    const float* xb = x + (size_t)b * NC * NVOX + v;
    float x0 = xb[0];
    float x1 = xb[NVOX];
    float x2 = xb[2 * NVOX];
    float x3 = xb[3 * NVOX];
    int p = 0; float m = x0;
    if (x1 > m) { m = x1; p = 1; }
    if (x2 > m) { m = x2; p = 2; }
    if (x3 > m) { m = x3; p = 3; }
    P[i] = (unsigned char)p;
    float s = expf(x0 - m) + expf(x1 - m) + expf(x2 - m) + expf(x3 - m);
    int yy = y[i];
    float xy = (yy == 0) ? x0 : ((yy == 1) ? x1 : ((yy == 2) ? x2 : x3));
    ce[i] = m + logf(s) - xy;
}

// Kernel 2: critical-voxel test (fused union of both interactions) + reduction.
// crit <=> (p==1 && exists nbr in {0,3}) || (p in {0,3} && exists nbr == 1)
// over the 3x3x3 zero-padded neighborhood (includes self; self never matters).
__global__ __launch_bounds__(256) void crit_sum_kernel(
    const unsigned char* __restrict__ P, const float* __restrict__ ce,
    float* __restrict__ out)
{
    int i = blockIdx.x * 256 + threadIdx.x;   // grid exactly covers TOTAL
    float val = 0.f;
    {
        int b = i >> 21;
        int v = i & (NVOX - 1);
        int d = v >> 14;           // Hh*Ww = 16384
        int r = v & 16383;
        int h = r >> 7;
        int w = r & 127;
        int p = P[i];
        if (p != 2) {
            const unsigned char* Pb = P + (size_t)b * NVOX;
            bool nbr1 = false, nbr03 = false;
            #pragma unroll
            for (int dz = -1; dz <= 1; ++dz) {
                int zd = d + dz; if ((unsigned)zd >= (unsigned)Dd) continue;
                #pragma unroll
                for (int dy = -1; dy <= 1; ++dy) {
                    int zh = h + dy; if ((unsigned)zh >= (unsigned)Hh) continue;
                    int base = (zd << 14) + (zh << 7);
                    #pragma unroll
                    for (int dx = -1; dx <= 1; ++dx) {
                        int zw = w + dx; if ((unsigned)zw >= (unsigned)Ww) continue;
                        int q = Pb[base + zw];
                        nbr1  |= (q == 1);
                        nbr03 |= (q != 1) & (q != 2);   // q in {0,3}
                    }
                }
            }
            bool crit = (p == 1) ? nbr03 : nbr1;   // here p in {0,1,3}
            if (crit) val = ce[i];
        }
    }
    // wave (64) shuffle reduction
    #pragma unroll
    for (int off = 32; off > 0; off >>= 1)
        val += __shfl_down(val, off, 64);
    __shared__ float wsum[4];
    int lane = threadIdx.x & 63;
    int wid  = threadIdx.x >> 6;
    if (lane == 0) wsum[wid] = val;
    __syncthreads();
    if (threadIdx.x == 0) {
        float s = wsum[0] + wsum[1] + wsum[2] + wsum[3];
        if (s != 0.f) atomicAdd(out, s * (1.0f / NB));   // mean over batch
    }
}

extern "C" void kernel_launch(void* const* d_in, const int* in_sizes, int n_in,
                              void* d_out, int out_size, void* d_ws, size_t ws_size,
                              hipStream_t stream) {
    const float* x = (const float*)d_in[0];
    const int*   y = (const int*)d_in[1];
    unsigned char* P = (unsigned char*)d_ws;                    // TOTAL bytes
    float* ce = (float*)((char*)d_ws + (size_t)TOTAL);          // TOTAL floats
    float* out = (float*)d_out;

    hipMemsetAsync(out, 0, sizeof(float), stream);
    argmax_ce_kernel<<<TOTAL / 256, 256, 0, stream>>>(x, y, P, ce);
    crit_sum_kernel<<<TOTAL / 256, 256, 0, stream>>>(P, ce, out);
}

// Round 2
// 114.814 us; speedup vs baseline: 2.8051x; 2.8051x over previous
//
#include <hip/hip_runtime.h>

constexpr int Dd = 128, Hh = 128, Ww = 128;
constexpr int NVOX = Dd * Hh * Ww;      // 2^21 per batch
constexpr int NB = 2;
constexpr int NC = 4;
constexpr int TOTAL = NB * NVOX;        // 4,194,304 voxels
constexpr int NWORDS = TOTAL / 64;      // 65536 mask words

struct alignas(16) MaskW { unsigned long long m1, m03; };

// Kernel 1: per-voxel argmax + CE; emit per-64-voxel predicate bitmasks via ballot.
// Wave handles 4 consecutive 64-voxel words (256 voxels). Lane l, word j -> voxel
// wavebase + 64*j + l, so __ballot() IS the mask word directly.
__global__ __launch_bounds__(256) void argmax_ce_kernel(
    const float* __restrict__ x, const int* __restrict__ y,
    MaskW* __restrict__ Mw, float* __restrict__ ce)
{
    int tid = threadIdx.x;
    int lane = tid & 63;
    int wavebase = blockIdx.x * 1024 + (tid >> 6) * 256;   // grid covers TOTAL exactly
    int b = wavebase >> 21;                                 // NVOX = 2^21
    int vb = wavebase & (NVOX - 1);
    const float* xb = x + (size_t)b * NC * NVOX;

    unsigned long long w1[4], w03[4];
    #pragma unroll
    for (int j = 0; j < 4; ++j) {
        int v = vb + 64 * j + lane;
        int g = wavebase + 64 * j + lane;
        float x0 = xb[v];
        float x1 = xb[v + NVOX];
        float x2 = xb[v + 2 * NVOX];
        float x3 = xb[v + 3 * NVOX];
        int p = 0; float m = x0;
        if (x1 > m) { m = x1; p = 1; }
        if (x2 > m) { m = x2; p = 2; }
        if (x3 > m) { m = x3; p = 3; }
        float s = expf(x0 - m) + expf(x1 - m) + expf(x2 - m) + expf(x3 - m);
        int yy = y[g];
        float xy = (yy == 0) ? x0 : ((yy == 1) ? x1 : ((yy == 2) ? x2 : x3));
        ce[g] = m + logf(s) - xy;
        w1[j]  = __ballot(p == 1);
        w03[j] = __ballot(p == 0 || p == 3);   // {0,3}
    }
    if (lane == 0) {
        int wbase = wavebase >> 6;
        #pragma unroll
        for (int j = 0; j < 4; ++j) {
            MaskW mw; mw.m1 = w1[j]; mw.m03 = w03[j];
            Mw[wbase + j] = mw;
        }
    }
}

// Kernel 2: one block per (b,d) plane. Stage 3 mask planes in LDS, compute the
// critical-voxel bitmask with word-level dilation, then reduce ce over set bits
// with coalesced float4 loads. One atomicAdd per block.
// crit <=> (p==1 && exists nbr in {0,3}) || (p in {0,3} && exists nbr == 1),
// 3x3x3 neighborhood, zero beyond volume borders.
__global__ __launch_bounds__(256) void crit_sum_kernel(
    const MaskW* __restrict__ Mw, const float* __restrict__ ce,
    float* __restrict__ out)
{
    __shared__ unsigned long long sm1[3][256];
    __shared__ unsigned long long sm03[3][256];
    __shared__ unsigned long long critw[256];
    __shared__ float wsum[4];

    int tid = threadIdx.x;
    int bid = blockIdx.x;          // b*128 + d
    int d = bid & 127;

    // stage planes d-1, d, d+1 (zero-fill out-of-range)
    #pragma unroll
    for (int pl = 0; pl < 3; ++pl) {
        int dp = d - 1 + pl;
        unsigned long long a = 0, c = 0;
        if ((unsigned)dp < 128u) {
            MaskW m = Mw[(bid - d + dp) * 256 + tid];
            a = m.m1; c = m.m03;
        }
        sm1[pl][tid] = a;
        sm03[pl][tid] = c;
    }
    __syncthreads();

    // this thread owns word (h = tid>>1, k = tid&1) of the center plane
    int h = tid >> 1, k = tid & 1;
    unsigned long long E1 = 0, E03 = 0;
    #pragma unroll
    for (int pl = 0; pl < 3; ++pl) {
        #pragma unroll
        for (int dy = -1; dy <= 1; ++dy) {
            int hh = h + dy;
            if ((unsigned)hh < 128u) {
                int idx = hh * 2 + k;
                int adj = hh * 2 + (k ^ 1);
                unsigned long long m1 = sm1[pl][idx],  a1 = sm1[pl][adj];
                unsigned long long m3 = sm03[pl][idx], a3 = sm03[pl][adj];
                unsigned long long s1 = m1 | (m1 << 1) | (m1 >> 1);
                unsigned long long s3 = m3 | (m3 << 1) | (m3 >> 1);
                if (k == 0) { s1 |= (a1 & 1ull) << 63; s3 |= (a3 & 1ull) << 63; }
                else        { s1 |= (a1 >> 63);        s3 |= (a3 >> 63); }
                E1  |= s1;
                E03 |= s3;
            }
        }
    }
    unsigned long long C1 = sm1[1][tid], C03 = sm03[1][tid];
    critw[tid] = (C1 & E03) | (C03 & E1);
    __syncthreads();

    // reduce ce over this plane's 16384 voxels, float4-coalesced
    const float4* cep = (const float4*)(ce + ((size_t)bid << 14));
    float s = 0.f;
    #pragma unroll
    for (int j = 0; j < 16; ++j) {
        float4 c = cep[j * 256 + tid];
        unsigned long long w = critw[j * 16 + (tid >> 4)];
        int bb = (tid & 15) * 4;
        if ((w >> bb)       & 1ull) s += c.x;
        if ((w >> (bb + 1)) & 1ull) s += c.y;
        if ((w >> (bb + 2)) & 1ull) s += c.z;
        if ((w >> (bb + 3)) & 1ull) s += c.w;
    }
    #pragma unroll
    for (int off = 32; off; off >>= 1) s += __shfl_down(s, off, 64);
    if ((tid & 63) == 0) wsum[tid >> 6] = s;
    __syncthreads();
    if (tid == 0) {
        float t = wsum[0] + wsum[1] + wsum[2] + wsum[3];
        atomicAdd(out, t * 0.5f);   // mean over NB=2 batches
    }
}

extern "C" void kernel_launch(void* const* d_in, const int* in_sizes, int n_in,
                              void* d_out, int out_size, void* d_ws, size_t ws_size,
                              hipStream_t stream) {
    const float* x = (const float*)d_in[0];
    const int*   y = (const int*)d_in[1];
    MaskW* Mw = (MaskW*)d_ws;                                   // 1 MB
    float* ce = (float*)((char*)d_ws + (size_t)NWORDS * 16);    // 16.8 MB
    float* out = (float*)d_out;

    hipMemsetAsync(out, 0, sizeof(float), stream);
    argmax_ce_kernel<<<TOTAL / 1024, 256, 0, stream>>>(x, y, Mw, ce);
    crit_sum_kernel<<<NB * Dd, 256, 0, stream>>>(Mw, ce, out);
}

// Round 3
// 107.652 us; speedup vs baseline: 2.9917x; 1.0665x over previous
//
#include <hip/hip_runtime.h>

constexpr int Dd = 128, Hh = 128, Ww = 128;
constexpr int NVOX = Dd * Hh * Ww;      // 2^21 per batch
constexpr int NB = 2;
constexpr int NC = 4;
constexpr int TOTAL = NB * NVOX;        // 4,194,304 voxels
constexpr int NWORDS = TOTAL / 64;      // 65536 mask words

struct alignas(16) MaskW { unsigned long long m1, m03; };

__device__ __forceinline__ unsigned short f2bf(float f) {
    unsigned int u = __float_as_uint(f);
    return (unsigned short)((u + 0x7FFFu + ((u >> 16) & 1u)) >> 16);  // RNE
}
__device__ __forceinline__ float bf2f_lo(unsigned int u) { return __uint_as_float(u << 16); }
__device__ __forceinline__ float bf2f_hi(unsigned int u) { return __uint_as_float(u & 0xFFFF0000u); }

// Kernel 1: 4 voxels/thread via float4/int4 loads. Computes argmax + CE (bf16),
// packs (p==1) and (p in {0,3}) predicate nibbles, assembles 64-voxel mask
// words through LDS. Also zeroes d_out (safe: kernel2 is stream-ordered after).
__global__ __launch_bounds__(256) void argmax_ce_kernel(
    const float4* __restrict__ x4, const int4* __restrict__ y4,
    MaskW* __restrict__ Mw, unsigned short* __restrict__ ce,
    float* __restrict__ out)
{
    int tid = threadIdx.x;
    if (blockIdx.x == 0 && tid == 0) out[0] = 0.f;

    int gv = blockIdx.x * 256 + tid;          // float4-group index (4 voxels)
    int b  = gv >> 19;                         // NVOX/4 = 2^19
    int vv = gv & ((NVOX / 4) - 1);
    const float4* xb = x4 + (size_t)b * (NC * NVOX / 4) + vv;
    float4 a0 = xb[0];
    float4 a1 = xb[NVOX / 4];
    float4 a2 = xb[2 * (NVOX / 4)];
    float4 a3 = xb[3 * (NVOX / 4)];
    int4 yi = y4[gv];

    float X0[4] = {a0.x, a0.y, a0.z, a0.w};
    float X1[4] = {a1.x, a1.y, a1.z, a1.w};
    float X2[4] = {a2.x, a2.y, a2.z, a2.w};
    float X3[4] = {a3.x, a3.y, a3.z, a3.w};
    int   Y[4]  = {yi.x, yi.y, yi.z, yi.w};

    unsigned int nib1 = 0, nib03 = 0;
    unsigned short cv[4];
    #pragma unroll
    for (int c = 0; c < 4; ++c) {
        float x0 = X0[c], x1 = X1[c], x2 = X2[c], x3 = X3[c];
        int p = 0; float m = x0;
        if (x1 > m) { m = x1; p = 1; }
        if (x2 > m) { m = x2; p = 2; }
        if (x3 > m) { m = x3; p = 3; }
        float s = expf(x0 - m) + expf(x1 - m) + expf(x2 - m) + expf(x3 - m);
        int yy = Y[c];
        float xy = (yy == 0) ? x0 : ((yy == 1) ? x1 : ((yy == 2) ? x2 : x3));
        cv[c] = f2bf(m + logf(s) - xy);
        nib1  |= (unsigned)(p == 1) << c;
        nib03 |= (unsigned)(p == 0 || p == 3) << c;
    }
    ushort4 cev = {cv[0], cv[1], cv[2], cv[3]};
    ((ushort4*)ce)[gv] = cev;                  // 8B/lane coalesced store

    // assemble mask words: block covers 1024 voxels = 16 words;
    // word w <- threads [16w,16w+16), nibble k at bit 4k.
    __shared__ unsigned int nibs[256];
    nibs[tid] = nib1 | (nib03 << 8);
    __syncthreads();
    if (tid < 16) {
        int base = tid * 16;
        unsigned long long m1 = 0, m03 = 0;
        #pragma unroll
        for (int k = 0; k < 16; ++k) {
            unsigned int nv = nibs[base + k];
            m1  |= (unsigned long long)(nv & 0xFu) << (4 * k);
            m03 |= (unsigned long long)((nv >> 8) & 0xFu) << (4 * k);
        }
        MaskW mw; mw.m1 = m1; mw.m03 = m03;
        Mw[blockIdx.x * 16 + tid] = mw;
    }
}

// Kernel 2: one block per (b,d) plane. Word-level 3x3x3 dilation of the
// predicate bitmasks -> critical mask; reduce bf16 ce over set bits with
// 16B-coalesced loads. One atomicAdd per block.
__global__ __launch_bounds__(256) void crit_sum_kernel(
    const MaskW* __restrict__ Mw, const unsigned short* __restrict__ ce,
    float* __restrict__ out)
{
    __shared__ unsigned long long sm1[3][256];
    __shared__ unsigned long long sm03[3][256];
    __shared__ unsigned long long critw[256];
    __shared__ float wsum[4];

    int tid = threadIdx.x;
    int bid = blockIdx.x;          // b*128 + d
    int d = bid & 127;

    #pragma unroll
    for (int pl = 0; pl < 3; ++pl) {
        int dp = d - 1 + pl;
        unsigned long long a = 0, c = 0;
        if ((unsigned)dp < 128u) {
            MaskW m = Mw[(bid - d + dp) * 256 + tid];
            a = m.m1; c = m.m03;
        }
        sm1[pl][tid] = a;
        sm03[pl][tid] = c;
    }
    __syncthreads();

    int h = tid >> 1, k = tid & 1;
    unsigned long long E1 = 0, E03 = 0;
    #pragma unroll
    for (int pl = 0; pl < 3; ++pl) {
        #pragma unroll
        for (int dy = -1; dy <= 1; ++dy) {
            int hh = h + dy;
            if ((unsigned)hh < 128u) {
                int idx = hh * 2 + k;
                int adj = hh * 2 + (k ^ 1);
                unsigned long long m1 = sm1[pl][idx],  a1 = sm1[pl][adj];
                unsigned long long m3 = sm03[pl][idx], a3 = sm03[pl][adj];
                unsigned long long s1 = m1 | (m1 << 1) | (m1 >> 1);
                unsigned long long s3 = m3 | (m3 << 1) | (m3 >> 1);
                if (k == 0) { s1 |= (a1 & 1ull) << 63; s3 |= (a3 & 1ull) << 63; }
                else        { s1 |= (a1 >> 63);        s3 |= (a3 >> 63); }
                E1  |= s1;
                E03 |= s3;
            }
        }
    }
    unsigned long long C1 = sm1[1][tid], C03 = sm03[1][tid];
    critw[tid] = (C1 & E03) | (C03 & E1);
    __syncthreads();

    // reduce ce (bf16) over this plane's 16384 voxels; uint4 = 8 voxels/lane
    const uint4* cep = (const uint4*)(ce + ((size_t)bid << 14));
    float s = 0.f;
    #pragma unroll
    for (int j = 0; j < 8; ++j) {
        int idx = j * 256 + tid;               // [0, 2048)
        uint4 u = cep[idx];
        unsigned long long w = critw[idx >> 3];
        int bb = (idx & 7) * 8;
        if ((w >> bb)       & 1ull) s += bf2f_lo(u.x);
        if ((w >> (bb + 1)) & 1ull) s += bf2f_hi(u.x);
        if ((w >> (bb + 2)) & 1ull) s += bf2f_lo(u.y);
        if ((w >> (bb + 3)) & 1ull) s += bf2f_hi(u.y);
        if ((w >> (bb + 4)) & 1ull) s += bf2f_lo(u.z);
        if ((w >> (bb + 5)) & 1ull) s += bf2f_hi(u.z);
        if ((w >> (bb + 6)) & 1ull) s += bf2f_lo(u.w);
        if ((w >> (bb + 7)) & 1ull) s += bf2f_hi(u.w);
    }
    #pragma unroll
    for (int off = 32; off; off >>= 1) s += __shfl_down(s, off, 64);
    if ((tid & 63) == 0) wsum[tid >> 6] = s;
    __syncthreads();
    if (tid == 0) {
        float t = wsum[0] + wsum[1] + wsum[2] + wsum[3];
        atomicAdd(out, t * 0.5f);   // mean over NB=2 batches
    }
}

extern "C" void kernel_launch(void* const* d_in, const int* in_sizes, int n_in,
                              void* d_out, int out_size, void* d_ws, size_t ws_size,
                              hipStream_t stream) {
    const float4* x4 = (const float4*)d_in[0];
    const int4*   y4 = (const int4*)d_in[1];
    MaskW* Mw = (MaskW*)d_ws;                                        // 1 MB
    unsigned short* ce = (unsigned short*)((char*)d_ws + (size_t)NWORDS * 16);  // 8.4 MB bf16
    float* out = (float*)d_out;

    argmax_ce_kernel<<<TOTAL / 1024, 256, 0, stream>>>(x4, y4, Mw, ce, out);
    crit_sum_kernel<<<NB * Dd, 256, 0, stream>>>(Mw, ce, out);
}